// Round 1
// baseline (501.650 us; speedup 1.0000x reference)
//
#include <hip/hip_runtime.h>

#define TPB 512
#define PAIRS_PER_BLOCK (TPB / 32)   // 16 parent-pairs (32 parents) per block

__global__ __launch_bounds__(TPB) void equi_unpool_kernel(
    const float* __restrict__ x_mv,    // [Np,32,16]
    const float* __restrict__ x_s,     // [Np,64]
    const float* __restrict__ skip_mv, // [Nc,32,16]
    const float* __restrict__ skip_s,  // [Nc,64]
    const float* __restrict__ w_mv,    // [32,32,9]
    const float* __restrict__ w_s2mv,  // [32,64]
    const float* __restrict__ w_mv2s,  // [64,32]
    const float* __restrict__ w_s2s,   // [64,64]
    const float* __restrict__ b_s,     // [64]
    float* __restrict__ out_mv,        // [Nc,32,16]
    float* __restrict__ out_s,         // [Nc,64]
    int n_parent, int stride)
{
    // LDS weight caches (53.8 KB total -> 2 blocks/CU)
    __shared__ float lw[9216];     // w_mv as [i][o][9]  (lane stride 9 -> conflict-free)
    __shared__ float ls2mv[2048];  // w_s2mv as [s][o]
    __shared__ float lmv2s[2048];  // w_mv2s as [i][ch]
    __shared__ float lbs[64];

    const int tid = threadIdx.x;
    for (int idx = tid; idx < 9216; idx += TPB) {
        int o = idx / 288;
        int r = idx - o * 288;
        int i = r / 9;
        int b = r - i * 9;
        lw[i * 288 + o * 9 + b] = w_mv[idx];
    }
    for (int idx = tid; idx < 2048; idx += TPB) {
        int o = idx >> 6, s = idx & 63;          // global [o][s]
        ls2mv[s * 32 + o] = w_s2mv[idx];
    }
    for (int idx = tid; idx < 2048; idx += TPB) {
        int ch = idx >> 5, i = idx & 31;         // global [ch][i]
        lmv2s[i * 64 + ch] = w_mv2s[idx];
    }
    if (tid < 64) lbs[tid] = b_s[tid];
    __syncthreads();

    const int o = tid & 31;        // output mv channel (also scalar ch o and o+32)
    const int g = tid >> 5;        // pair slot within block
    const int pair = blockIdx.x * PAIRS_PER_BLOCK + g;
    const int np2 = (n_parent + 1) >> 1;
    if (pair >= np2) return;

    const int p0 = pair * 2;
    const int p1 = p0 + 1;
    const bool hasB = (p1 < n_parent);
    const int pB = hasB ? p1 : p0;

    float a0[16], a1[16];
#pragma unroll
    for (int j = 0; j < 16; ++j) { a0[j] = 0.f; a1[j] = 0.f; }
    float sA0 = 0.f, sA1 = 0.f, sB0 = 0.f, sB1 = 0.f;

    const float4* xA = (const float4*)(x_mv + (size_t)p0 * 512);
    const float4* xB = (const float4*)(x_mv + (size_t)pB * 512);

#pragma unroll 4
    for (int i = 0; i < 32; ++i) {
        float4 A0 = xA[i * 4 + 0], A1 = xA[i * 4 + 1], A2 = xA[i * 4 + 2], A3 = xA[i * 4 + 3];
        float4 B0 = xB[i * 4 + 0], B1 = xB[i * 4 + 1], B2 = xB[i * 4 + 2], B3 = xB[i * 4 + 3];
        const float* wr = &lw[i * 288 + o * 9];
        float w0 = wr[0], w1 = wr[1], w2 = wr[2], w3 = wr[3], w4 = wr[4];
        float w5 = wr[5], w6 = wr[6], w7 = wr[7], w8 = wr[8];

        // parent A: grade projections + e0-wedge
        a0[0]  += A0.x * w0;
        a0[1]  += A0.y * w1 + A0.x * w5;
        a0[2]  += A0.z * w1;
        a0[3]  += A0.w * w1;
        a0[4]  += A1.x * w1;
        a0[5]  += A1.y * w2 + A0.z * w6;
        a0[6]  += A1.z * w2 + A0.w * w6;
        a0[7]  += A1.w * w2 + A1.x * w6;
        a0[8]  += A2.x * w2;
        a0[9]  += A2.y * w2;
        a0[10] += A2.z * w2;
        a0[11] += A2.w * w3 + A2.x * w7;
        a0[12] += A3.x * w3 + A2.y * w7;
        a0[13] += A3.y * w3 + A2.z * w7;
        a0[14] += A3.z * w3;
        a0[15] += A3.w * w4 + A3.z * w8;
        // parent B
        a1[0]  += B0.x * w0;
        a1[1]  += B0.y * w1 + B0.x * w5;
        a1[2]  += B0.z * w1;
        a1[3]  += B0.w * w1;
        a1[4]  += B1.x * w1;
        a1[5]  += B1.y * w2 + B0.z * w6;
        a1[6]  += B1.z * w2 + B0.w * w6;
        a1[7]  += B1.w * w2 + B1.x * w6;
        a1[8]  += B2.x * w2;
        a1[9]  += B2.y * w2;
        a1[10] += B2.z * w2;
        a1[11] += B2.w * w3 + B2.x * w7;
        a1[12] += B3.x * w3 + B2.y * w7;
        a1[13] += B3.y * w3 + B2.z * w7;
        a1[14] += B3.z * w3;
        a1[15] += B3.w * w4 + B3.z * w8;

        // mv scalar-component -> out_s (x[i][0] already in registers)
        float wm0 = lmv2s[i * 64 + o];
        float wm1 = lmv2s[i * 64 + o + 32];
        sA0 += A0.x * wm0; sA1 += A0.x * wm1;
        sB0 += B0.x * wm0; sB1 += B0.x * wm1;
    }

    // scalar inputs: s2mv (into a*[0]) and s2s (into s* accumulators)
    const float4* xsA = (const float4*)(x_s + (size_t)p0 * 64);
    const float4* xsB = (const float4*)(x_s + (size_t)pB * 64);
    const float4* wsR0 = (const float4*)(w_s2s + (size_t)o * 64);        // row ch=o
    const float4* wsR1 = (const float4*)(w_s2s + (size_t)(o + 32) * 64); // row ch=o+32
#pragma unroll 4
    for (int sc = 0; sc < 16; ++sc) {
        float4 xa = xsA[sc], xb = xsB[sc];
        float4 wa = wsR0[sc], wb = wsR1[sc];
        float m0 = ls2mv[(sc * 4 + 0) * 32 + o];
        float m1 = ls2mv[(sc * 4 + 1) * 32 + o];
        float m2 = ls2mv[(sc * 4 + 2) * 32 + o];
        float m3 = ls2mv[(sc * 4 + 3) * 32 + o];
        a0[0] += xa.x * m0 + xa.y * m1 + xa.z * m2 + xa.w * m3;
        a1[0] += xb.x * m0 + xb.y * m1 + xb.z * m2 + xb.w * m3;
        sA0 += xa.x * wa.x + xa.y * wa.y + xa.z * wa.z + xa.w * wa.w;
        sA1 += xa.x * wb.x + xa.y * wb.y + xa.z * wb.z + xa.w * wb.w;
        sB0 += xb.x * wa.x + xb.y * wa.y + xb.z * wa.z + xb.w * wa.w;
        sB1 += xb.x * wb.x + xb.y * wb.y + xb.z * wb.z + xb.w * wb.w;
    }

    float bs0 = lbs[o], bs1 = lbs[o + 32];
    sA0 += bs0; sA1 += bs1;
    sB0 += bs0; sB1 += bs1;

    // epilogue: broadcast to children, add skip, store
    for (int r = 0; r < stride; ++r) {
        int c = p0 * stride + r;
        const float4* sk = (const float4*)(skip_mv + (size_t)c * 512 + o * 16);
        float4* om = (float4*)(out_mv + (size_t)c * 512 + o * 16);
        float4 s0 = sk[0], s1 = sk[1], s2 = sk[2], s3 = sk[3];
        om[0] = make_float4(s0.x + a0[0],  s0.y + a0[1],  s0.z + a0[2],  s0.w + a0[3]);
        om[1] = make_float4(s1.x + a0[4],  s1.y + a0[5],  s1.z + a0[6],  s1.w + a0[7]);
        om[2] = make_float4(s2.x + a0[8],  s2.y + a0[9],  s2.z + a0[10], s2.w + a0[11]);
        om[3] = make_float4(s3.x + a0[12], s3.y + a0[13], s3.z + a0[14], s3.w + a0[15]);
        out_s[(size_t)c * 64 + o]      = skip_s[(size_t)c * 64 + o] + sA0;
        out_s[(size_t)c * 64 + o + 32] = skip_s[(size_t)c * 64 + o + 32] + sA1;
    }
    if (hasB) {
        for (int r = 0; r < stride; ++r) {
            int c = p1 * stride + r;
            const float4* sk = (const float4*)(skip_mv + (size_t)c * 512 + o * 16);
            float4* om = (float4*)(out_mv + (size_t)c * 512 + o * 16);
            float4 s0 = sk[0], s1 = sk[1], s2 = sk[2], s3 = sk[3];
            om[0] = make_float4(s0.x + a1[0],  s0.y + a1[1],  s0.z + a1[2],  s0.w + a1[3]);
            om[1] = make_float4(s1.x + a1[4],  s1.y + a1[5],  s1.z + a1[6],  s1.w + a1[7]);
            om[2] = make_float4(s2.x + a1[8],  s2.y + a1[9],  s2.z + a1[10], s2.w + a1[11]);
            om[3] = make_float4(s3.x + a1[12], s3.y + a1[13], s3.z + a1[14], s3.w + a1[15]);
            out_s[(size_t)c * 64 + o]      = skip_s[(size_t)c * 64 + o] + sB0;
            out_s[(size_t)c * 64 + o + 32] = skip_s[(size_t)c * 64 + o + 32] + sB1;
        }
    }
}

extern "C" void kernel_launch(void* const* d_in, const int* in_sizes, int n_in,
                              void* d_out, int out_size, void* d_ws, size_t ws_size,
                              hipStream_t stream) {
    const float* x_mv    = (const float*)d_in[0];
    const float* x_s     = (const float*)d_in[1];
    const float* skip_mv = (const float*)d_in[2];
    const float* skip_s  = (const float*)d_in[3];
    const float* w_mv    = (const float*)d_in[4];
    const float* w_s2mv  = (const float*)d_in[5];
    const float* w_mv2s  = (const float*)d_in[6];
    const float* w_s2s   = (const float*)d_in[7];
    const float* b_s     = (const float*)d_in[8];

    const int n_parent = in_sizes[0] / 512;   // [Np,32,16]
    const int n_child  = in_sizes[2] / 512;   // [Nc,32,16]
    const int stride   = n_child / n_parent;

    float* out_mv = (float*)d_out;
    float* out_s  = out_mv + (size_t)n_child * 512;

    const int np2 = (n_parent + 1) >> 1;
    const int blocks = (np2 + PAIRS_PER_BLOCK - 1) / PAIRS_PER_BLOCK;
    equi_unpool_kernel<<<blocks, TPB, 0, stream>>>(
        x_mv, x_s, skip_mv, skip_s, w_mv, w_s2mv, w_mv2s, w_s2s, b_s,
        out_mv, out_s, n_parent, stride);
}

// Round 2
// 404.530 us; speedup vs baseline: 1.2401x; 1.2401x over previous
//
#include <hip/hip_runtime.h>
#include <stdint.h>

#define TPB 512
#define P_BLK 16   // parents per block; 32KB x-tile in LDS

__device__ __forceinline__ void load_lds16(const float* gsrc, float* ldsdst) {
    // width-16 global->LDS DMA: per-lane global src, wave-uniform LDS base (+lane*16 by HW)
    __builtin_amdgcn_global_load_lds((const __attribute__((address_space(1))) void*)gsrc,
                                     (__attribute__((address_space(3))) void*)ldsdst,
                                     16, 0, 0);
}

__global__ __launch_bounds__(TPB, 4) void equi_unpool_v2(
    const float* __restrict__ x_mv,    // [Np,32,16]
    const float* __restrict__ x_s,     // [Np,64]
    const float* __restrict__ skip_mv, // [Nc,32,16]
    const float* __restrict__ skip_s,  // [Nc,64]
    const float* __restrict__ w_mv,    // [32,32,9]
    const float* __restrict__ w_s2mv,  // [32,64]
    const float* __restrict__ w_mv2s,  // [64,32]
    const float* __restrict__ w_s2s,   // [64,64]
    const float* __restrict__ b_s,     // [64]
    float* __restrict__ out_mv,        // [Nc,32,16]
    float* __restrict__ out_s,         // [Nc,64]
    int n_parent, int stride)
{
    __shared__ float xs[P_BLK * 512];   // 32 KB: x_mv tile, linear (same layout as global)
    __shared__ float lwb[9 * 1024];     // 36 KB: w_mv as [b][i][o] -> consecutive-lane b32 reads
    __shared__ float lmv2s[2048];       //  8 KB: w_mv2s as [i][ch]
    __shared__ float lbs[64];           // total 78,080 B -> 2 blocks/CU

    const int tid = threadIdx.x;
    const int p0 = blockIdx.x * P_BLK;
    const int avail = n_parent - p0;

    // ---- stage x_mv tile (coalesced, async, deep MLP) ----
    if (avail >= P_BLK) {
        const int lane = tid & 63;
        const int wv   = tid >> 6;                       // 8 waves
        const float* gb = x_mv + (size_t)p0 * 512;
        #pragma unroll
        for (int c = 0; c < 4; ++c) {
            const int base = wv * 1024 + c * 256;        // float offset, wave-uniform
            load_lds16(gb + base + lane * 4, &xs[base]); // HW adds lane*16B on LDS side
        }
    } else {
        const int total = avail * 512;
        for (int k = tid; k < total; k += TPB) xs[k] = x_mv[(size_t)p0 * 512 + k];
    }

    // ---- stage weights (one-time per block) ----
    for (int idx = tid; idx < 9216; idx += TPB) {
        int o = idx / 288;
        int r = idx - o * 288;
        int i = r / 9;
        int b = r - i * 9;
        lwb[b * 1024 + i * 32 + o] = w_mv[idx];
    }
    for (int idx = tid; idx < 2048; idx += TPB) {
        int ch = idx >> 5, i = idx & 31;                 // global [ch][i]
        lmv2s[i * 64 + ch] = w_mv2s[idx];
    }
    if (tid < 64) lbs[tid] = b_s[tid];
    __syncthreads();

    const int o  = tid & 31;     // output mv channel; also scalar channels o, o+32
    const int pl = tid >> 5;     // local parent
    const int p  = p0 + pl;
    if (p >= n_parent) return;

    float a[16];
    #pragma unroll
    for (int j = 0; j < 16; ++j) a[j] = 0.f;
    float s0 = 0.f, s1 = 0.f;

    const float* xb = &xs[pl * 512];

    #pragma unroll 4
    for (int i = 0; i < 32; ++i) {
        float4 X0 = *(const float4*)(xb + i * 16 + 0);
        float4 X1 = *(const float4*)(xb + i * 16 + 4);
        float4 X2 = *(const float4*)(xb + i * 16 + 8);
        float4 X3 = *(const float4*)(xb + i * 16 + 12);
        const float* wp = &lwb[i * 32 + o];
        float w0 = wp[0 * 1024], w1 = wp[1 * 1024], w2 = wp[2 * 1024];
        float w3 = wp[3 * 1024], w4 = wp[4 * 1024], w5 = wp[5 * 1024];
        float w6 = wp[6 * 1024], w7 = wp[7 * 1024], w8 = wp[8 * 1024];

        a[0]  += X0.x * w0;
        a[1]  += X0.y * w1 + X0.x * w5;
        a[2]  += X0.z * w1;
        a[3]  += X0.w * w1;
        a[4]  += X1.x * w1;
        a[5]  += X1.y * w2 + X0.z * w6;
        a[6]  += X1.z * w2 + X0.w * w6;
        a[7]  += X1.w * w2 + X1.x * w6;
        a[8]  += X2.x * w2;
        a[9]  += X2.y * w2;
        a[10] += X2.z * w2;
        a[11] += X2.w * w3 + X2.x * w7;
        a[12] += X3.x * w3 + X2.y * w7;
        a[13] += X3.y * w3 + X2.z * w7;
        a[14] += X3.z * w3;
        a[15] += X3.w * w4 + X3.z * w8;

        float wm0 = lmv2s[i * 64 + o];
        float wm1 = lmv2s[i * 64 + o + 32];
        s0 += X0.x * wm0;
        s1 += X0.x * wm1;
    }

    // ---- scalar inputs: s2mv (into a[0]) and s2s ----
    const float4* xsv = (const float4*)(x_s + (size_t)p * 64);
    const float4* wmv = (const float4*)(w_s2mv + (size_t)o * 64);         // row o
    const float4* wsa = (const float4*)(w_s2s + (size_t)o * 64);          // row ch=o
    const float4* wsb = (const float4*)(w_s2s + (size_t)(o + 32) * 64);   // row ch=o+32
    #pragma unroll 4
    for (int sc = 0; sc < 16; ++sc) {
        float4 xv = xsv[sc], m = wmv[sc], wa = wsa[sc], wb = wsb[sc];
        a[0] += xv.x * m.x + xv.y * m.y + xv.z * m.z + xv.w * m.w;
        s0   += xv.x * wa.x + xv.y * wa.y + xv.z * wa.z + xv.w * wa.w;
        s1   += xv.x * wb.x + xv.y * wb.y + xv.z * wb.z + xv.w * wb.w;
    }
    s0 += lbs[o];
    s1 += lbs[o + 32];

    // ---- epilogue: broadcast to children, add skip, store (coalesced) ----
    for (int r = 0; r < stride; ++r) {
        size_t c = (size_t)p * stride + r;
        const float4* sk = (const float4*)(skip_mv + c * 512 + o * 16);
        float4* om = (float4*)(out_mv + c * 512 + o * 16);
        float4 k0 = sk[0], k1 = sk[1], k2 = sk[2], k3 = sk[3];
        om[0] = make_float4(k0.x + a[0],  k0.y + a[1],  k0.z + a[2],  k0.w + a[3]);
        om[1] = make_float4(k1.x + a[4],  k1.y + a[5],  k1.z + a[6],  k1.w + a[7]);
        om[2] = make_float4(k2.x + a[8],  k2.y + a[9],  k2.z + a[10], k2.w + a[11]);
        om[3] = make_float4(k3.x + a[12], k3.y + a[13], k3.z + a[14], k3.w + a[15]);
        out_s[c * 64 + o]      = skip_s[c * 64 + o] + s0;
        out_s[c * 64 + o + 32] = skip_s[c * 64 + o + 32] + s1;
    }
}

extern "C" void kernel_launch(void* const* d_in, const int* in_sizes, int n_in,
                              void* d_out, int out_size, void* d_ws, size_t ws_size,
                              hipStream_t stream) {
    const float* x_mv    = (const float*)d_in[0];
    const float* x_s     = (const float*)d_in[1];
    const float* skip_mv = (const float*)d_in[2];
    const float* skip_s  = (const float*)d_in[3];
    const float* w_mv    = (const float*)d_in[4];
    const float* w_s2mv  = (const float*)d_in[5];
    const float* w_mv2s  = (const float*)d_in[6];
    const float* w_s2s   = (const float*)d_in[7];
    const float* b_s     = (const float*)d_in[8];

    const int n_parent = in_sizes[0] / 512;   // [Np,32,16]
    const int n_child  = in_sizes[2] / 512;   // [Nc,32,16]
    const int stride   = n_child / n_parent;

    float* out_mv = (float*)d_out;
    float* out_s  = out_mv + (size_t)n_child * 512;

    const int blocks = (n_parent + P_BLK - 1) / P_BLK;
    equi_unpool_v2<<<blocks, TPB, 0, stream>>>(
        x_mv, x_s, skip_mv, skip_s, w_mv, w_s2mv, w_mv2s, w_s2s, b_s,
        out_mv, out_s, n_parent, stride);
}